// Round 1
// baseline (994.808 us; speedup 1.0000x reference)
//
#include <hip/hip_runtime.h>
#include <hip/hip_bf16.h>
#include <math.h>

#define NNODES 100000
#define EPSV 1e-5f

// ---------------- graph prep ----------------

__global__ __launch_bounds__(256) void zero_i32_k(int* __restrict__ p, int n) {
  int i = blockIdx.x * 256 + threadIdx.x;
  if (i < n) p[i] = 0;
}

__global__ __launch_bounds__(256) void count_deg_k(const int* __restrict__ ei, int E,
                                                   int* __restrict__ deg) {
  for (int e = blockIdx.x * blockDim.x + threadIdx.x; e < E; e += gridDim.x * blockDim.x)
    atomicAdd(&deg[ei[E + e]], 1);
}

// inclusive scan of 256-chunks; writes inclusive values into rowst, chunk totals into chunk
__global__ __launch_bounds__(256) void scanA_k(const int* __restrict__ cnt, int* __restrict__ rowst,
                                               int* __restrict__ chunk, int n) {
  __shared__ int sm[256];
  int i = blockIdx.x * 256 + threadIdx.x;
  int v = (i < n) ? cnt[i] : 0;
  sm[threadIdx.x] = v;
  __syncthreads();
  for (int off = 1; off < 256; off <<= 1) {
    int t = (threadIdx.x >= off) ? sm[threadIdx.x - off] : 0;
    __syncthreads();
    sm[threadIdx.x] += t;
    __syncthreads();
  }
  if (i < n) rowst[i] = sm[threadIdx.x];
  if (threadIdx.x == 255) chunk[blockIdx.x] = sm[255];
}

// exclusive scan of chunk sums in-place (nc <= 512)
__global__ __launch_bounds__(512) void scanB_k(int* __restrict__ chunk, int nc) {
  __shared__ int sm[512];
  int v = (threadIdx.x < nc) ? chunk[threadIdx.x] : 0;
  sm[threadIdx.x] = v;
  __syncthreads();
  for (int off = 1; off < 512; off <<= 1) {
    int t = (threadIdx.x >= off) ? sm[threadIdx.x - off] : 0;
    __syncthreads();
    sm[threadIdx.x] += t;
    __syncthreads();
  }
  if (threadIdx.x < nc) chunk[threadIdx.x] = sm[threadIdx.x] - v;
}

__global__ __launch_bounds__(256) void scanC_k(const int* __restrict__ cnt, const int* __restrict__ chunk,
                                               int* __restrict__ rowst, int* __restrict__ cursor, int n) {
  int i = blockIdx.x * 256 + threadIdx.x;
  if (i < n) {
    int ex = chunk[blockIdx.x] + rowst[i] - cnt[i];
    rowst[i] = ex;
    cursor[i] = ex;
  }
}

__global__ __launch_bounds__(256) void dinv_k(const int* __restrict__ deg, float* __restrict__ dinv, int n) {
  int i = blockIdx.x * 256 + threadIdx.x;
  if (i < n) dinv[i] = rsqrtf((float)deg[i] + 1.0f);
}

__global__ __launch_bounds__(256) void fill_k(const int* __restrict__ ei, int E,
                                              int* __restrict__ cursor, int* __restrict__ csr) {
  for (int e = blockIdx.x * blockDim.x + threadIdx.x; e < E; e += gridDim.x * blockDim.x) {
    int s = ei[e];
    int d = ei[E + e];
    int pos = atomicAdd(&cursor[d], 1);
    csr[pos] = s;
  }
}

// ---------------- GEMM: y[r][c] = dinv[r] * sum_k z[r][k] * W[k][c] ----------------
// z = BN ? relu(in*scale + shift) : in.   BM=64, K=128 fixed.

template <int NOUT, bool BN>
__global__ __launch_bounds__(256) void gemm_k(const float* __restrict__ in, const float* __restrict__ W,
                                              const float* __restrict__ scale, const float* __restrict__ shift,
                                              const float* __restrict__ dinv, float* __restrict__ y, int n) {
  __shared__ float zs[64][132];       // +4 pad: bank spread for column reads
  __shared__ float wsm[128 * NOUT];
  const int tid = threadIdx.x;
  const int row0 = blockIdx.x * 64;

  for (int f = tid * 4; f < 128 * NOUT; f += 1024)
    *(float4*)&wsm[f] = *(const float4*)&W[f];

#pragma unroll
  for (int it = 0; it < 8; ++it) {
    int f = tid + it * 256;          // float4 id 0..2047
    int r = f >> 5, c4 = (f & 31) * 4;
    int row = row0 + r;
    float4 v;
    if (row < n) v = *(const float4*)&in[(size_t)row * 128 + c4];
    else v = make_float4(0.f, 0.f, 0.f, 0.f);
    if (BN) {
      float4 sc = *(const float4*)&scale[c4];
      float4 sh = *(const float4*)&shift[c4];
      v.x = fmaxf(fmaf(v.x, sc.x, sh.x), 0.f);
      v.y = fmaxf(fmaf(v.y, sc.y, sh.y), 0.f);
      v.z = fmaxf(fmaf(v.z, sc.z, sh.z), 0.f);
      v.w = fmaxf(fmaf(v.w, sc.w, sh.w), 0.f);
    }
    *(float4*)&zs[r][c4] = v;
  }
  __syncthreads();

  if constexpr (NOUT == 128) {
    const int tr = tid >> 4, tc = tid & 15;
    const int r0 = tr * 4, c0 = tc * 8;
    float acc[4][8];
#pragma unroll
    for (int i = 0; i < 4; ++i)
#pragma unroll
      for (int j = 0; j < 8; ++j) acc[i][j] = 0.f;

#pragma unroll 4
    for (int k = 0; k < 128; ++k) {
      float a[4];
#pragma unroll
      for (int i = 0; i < 4; ++i) a[i] = zs[r0 + i][k];
      float4 b0 = *(const float4*)&wsm[k * 128 + c0];
      float4 b1 = *(const float4*)&wsm[k * 128 + c0 + 4];
#pragma unroll
      for (int i = 0; i < 4; ++i) {
        acc[i][0] = fmaf(a[i], b0.x, acc[i][0]);
        acc[i][1] = fmaf(a[i], b0.y, acc[i][1]);
        acc[i][2] = fmaf(a[i], b0.z, acc[i][2]);
        acc[i][3] = fmaf(a[i], b0.w, acc[i][3]);
        acc[i][4] = fmaf(a[i], b1.x, acc[i][4]);
        acc[i][5] = fmaf(a[i], b1.y, acc[i][5]);
        acc[i][6] = fmaf(a[i], b1.z, acc[i][6]);
        acc[i][7] = fmaf(a[i], b1.w, acc[i][7]);
      }
    }
#pragma unroll
    for (int i = 0; i < 4; ++i) {
      int row = row0 + r0 + i;
      if (row < n) {
        float dv = dinv[row];
        float4 o0, o1;
        o0.x = acc[i][0] * dv; o0.y = acc[i][1] * dv; o0.z = acc[i][2] * dv; o0.w = acc[i][3] * dv;
        o1.x = acc[i][4] * dv; o1.y = acc[i][5] * dv; o1.z = acc[i][6] * dv; o1.w = acc[i][7] * dv;
        *(float4*)&y[(size_t)row * 128 + c0] = o0;
        *(float4*)&y[(size_t)row * 128 + c0 + 4] = o1;
      }
    }
  } else {  // NOUT == 40
    const int r = tid >> 2;
    const int c0 = (tid & 3) * 10;
    float acc[10];
#pragma unroll
    for (int j = 0; j < 10; ++j) acc[j] = 0.f;
#pragma unroll 4
    for (int k = 0; k < 128; ++k) {
      float a = zs[r][k];
#pragma unroll
      for (int j = 0; j < 10; ++j) acc[j] = fmaf(a, wsm[k * NOUT + c0 + j], acc[j]);
    }
    int row = row0 + r;
    if (row < n) {
      float dv = dinv[row];
#pragma unroll
      for (int j = 0; j < 10; ++j) y[(size_t)row * NOUT + c0 + j] = acc[j] * dv;
    }
  }
}

// ---------------- aggregation: out[n] = dinv[n]*(sum_{s in adj(n)} y[s] + y[n]) + bias ----------------

__global__ __launch_bounds__(256) void agg128_k(const float* __restrict__ y, const int* __restrict__ csr,
                                                const int* __restrict__ rowst, const int* __restrict__ deg,
                                                const float* __restrict__ dinv, const float* __restrict__ bias,
                                                float* __restrict__ out, int n) {
  int wid = (blockIdx.x * 256 + threadIdx.x) >> 6;
  if (wid >= n) return;
  int lane = threadIdx.x & 63;
  int base = rowst[wid];
  int dg = deg[wid];
  size_t co = (size_t)(lane * 2);
  float a0 = 0.f, a1 = 0.f, b0 = 0.f, b1 = 0.f, c0 = 0.f, c1 = 0.f, d0 = 0.f, d1 = 0.f;
  int t = 0;
  for (; t + 4 <= dg; t += 4) {
    int s0 = csr[base + t], s1 = csr[base + t + 1], s2 = csr[base + t + 2], s3 = csr[base + t + 3];
    float2 v0 = *(const float2*)&y[(size_t)s0 * 128 + co];
    float2 v1 = *(const float2*)&y[(size_t)s1 * 128 + co];
    float2 v2 = *(const float2*)&y[(size_t)s2 * 128 + co];
    float2 v3 = *(const float2*)&y[(size_t)s3 * 128 + co];
    a0 += v0.x; a1 += v0.y; b0 += v1.x; b1 += v1.y;
    c0 += v2.x; c1 += v2.y; d0 += v3.x; d1 += v3.y;
  }
  for (; t < dg; ++t) {
    int s = csr[base + t];
    float2 v = *(const float2*)&y[(size_t)s * 128 + co];
    a0 += v.x; a1 += v.y;
  }
  float2 vs = *(const float2*)&y[(size_t)wid * 128 + co];
  a0 += vs.x; a1 += vs.y;
  float s0 = (a0 + b0) + (c0 + d0);
  float s1 = (a1 + b1) + (c1 + d1);
  float dv = dinv[wid];
  float2 bb = *(const float2*)&bias[lane * 2];
  float2 o;
  o.x = fmaf(s0, dv, bb.x);
  o.y = fmaf(s1, dv, bb.y);
  *(float2*)&out[(size_t)wid * 128 + co] = o;
}

// last layer: aggregation (d=40) + bias + log_softmax fused
__global__ __launch_bounds__(256) void agg40_lsm_k(const float* __restrict__ y, const int* __restrict__ csr,
                                                   const int* __restrict__ rowst, const int* __restrict__ deg,
                                                   const float* __restrict__ dinv, const float* __restrict__ bias,
                                                   float* __restrict__ out, int n) {
  int wid = (blockIdx.x * 256 + threadIdx.x) >> 6;
  if (wid >= n) return;
  int lane = threadIdx.x & 63;
  int col = lane < 40 ? lane : 39;
  int base = rowst[wid];
  int dg = deg[wid];
  float a = 0.f, b = 0.f, c = 0.f, d = 0.f;
  int t = 0;
  for (; t + 4 <= dg; t += 4) {
    int s0 = csr[base + t], s1 = csr[base + t + 1], s2 = csr[base + t + 2], s3 = csr[base + t + 3];
    a += y[(size_t)s0 * 40 + col];
    b += y[(size_t)s1 * 40 + col];
    c += y[(size_t)s2 * 40 + col];
    d += y[(size_t)s3 * 40 + col];
  }
  for (; t < dg; ++t) {
    int s = csr[base + t];
    a += y[(size_t)s * 40 + col];
  }
  a += y[(size_t)wid * 40 + col];
  float v = fmaf((a + b) + (c + d), dinv[wid], bias[col]);
  bool act = lane < 40;
  float m = act ? v : -INFINITY;
#pragma unroll
  for (int off = 32; off; off >>= 1) m = fmaxf(m, __shfl_xor(m, off));
  float e = act ? expf(v - m) : 0.f;
  float se = e;
#pragma unroll
  for (int off = 32; off; off >>= 1) se += __shfl_xor(se, off);
  if (act) out[(size_t)wid * 40 + lane] = v - m - logf(se);
}

// ---------------- BN stats ----------------

__global__ __launch_bounds__(256) void stats_partial_k(const float* __restrict__ h,
                                                       float* __restrict__ ps, float* __restrict__ pss, int n) {
  int c = threadIdx.x & 127;
  int half = threadIdx.x >> 7;
  int r0 = blockIdx.x * 2 + half;   // grid must be 256 blocks -> 512 row streams
  float s = 0.f, ss = 0.f;
  for (int r = r0; r < n; r += 512) {
    float v = h[(size_t)r * 128 + c];
    s += v;
    ss = fmaf(v, v, ss);
  }
  __shared__ float sm[256], sm2[256];
  sm[threadIdx.x] = s;
  sm2[threadIdx.x] = ss;
  __syncthreads();
  if (threadIdx.x < 128) {
    ps[blockIdx.x * 128 + c] = sm[c] + sm[c + 128];
    pss[blockIdx.x * 128 + c] = sm2[c] + sm2[c + 128];
  }
}

__global__ __launch_bounds__(128) void stats_final_k(const float* __restrict__ ps, const float* __restrict__ pss,
                                                     const float* __restrict__ g, const float* __restrict__ be,
                                                     float* __restrict__ scale, float* __restrict__ shift, int n) {
  int c = threadIdx.x;  // 128 threads
  float s = 0.f, ss = 0.f;
  for (int b = 0; b < 256; ++b) {
    s += ps[b * 128 + c];
    ss += pss[b * 128 + c];
  }
  float mu = s / (float)n;
  float var = ss / (float)n - mu * mu;
  float rs = rsqrtf(var + EPSV);
  float sc = rs * g[c];
  scale[c] = sc;
  shift[c] = fmaf(-mu, sc, be[c]);
}

// ---------------- launch ----------------

extern "C" void kernel_launch(void* const* d_in, const int* in_sizes, int n_in,
                              void* d_out, int out_size, void* d_ws, size_t ws_size,
                              hipStream_t stream) {
  const float* x   = (const float*)d_in[0];
  const int*   ei  = (const int*)d_in[1];
  const float* W1  = (const float*)d_in[2];
  const float* b1  = (const float*)d_in[3];
  const float* W2  = (const float*)d_in[4];
  const float* b2  = (const float*)d_in[5];
  const float* W3  = (const float*)d_in[6];
  const float* b3  = (const float*)d_in[7];
  const float* g1  = (const float*)d_in[8];
  const float* be1 = (const float*)d_in[9];
  const float* g2  = (const float*)d_in[10];
  const float* be2 = (const float*)d_in[11];
  float* outp = (float*)d_out;

  const int N = NNODES;
  const int E = in_sizes[1] / 2;
  const int NC = (N + 255) / 256;  // 391

  char* w = (char*)d_ws;
  auto alloc = [&](size_t bytes) -> void* {
    void* p = (void*)w;
    w += (bytes + 255) & ~(size_t)255;
    return p;
  };
  int*   deg    = (int*)alloc((size_t)N * 4);
  int*   rowst  = (int*)alloc((size_t)N * 4);
  int*   cursor = (int*)alloc((size_t)N * 4);
  int*   chunk  = (int*)alloc((size_t)(NC + 1) * 4);
  int*   csr    = (int*)alloc((size_t)E * 4);
  float* dinv   = (float*)alloc((size_t)N * 4);
  float* y      = (float*)alloc((size_t)N * 128 * 4);
  float* hpre   = (float*)alloc((size_t)N * 128 * 4);
  float* ps     = (float*)alloc((size_t)256 * 128 * 4);
  float* pss    = (float*)alloc((size_t)256 * 128 * 4);
  float* scl    = (float*)alloc(128 * 4);
  float* shf    = (float*)alloc(128 * 4);

  // graph prep
  zero_i32_k<<<(N + 255) / 256, 256, 0, stream>>>(deg, N);
  count_deg_k<<<2048, 256, 0, stream>>>(ei, E, deg);
  scanA_k<<<NC, 256, 0, stream>>>(deg, rowst, chunk, N);
  scanB_k<<<1, 512, 0, stream>>>(chunk, NC);
  scanC_k<<<NC, 256, 0, stream>>>(deg, chunk, rowst, cursor, N);
  dinv_k<<<(N + 255) / 256, 256, 0, stream>>>(deg, dinv, N);
  fill_k<<<2048, 256, 0, stream>>>(ei, E, cursor, csr);

  const int GB = (N + 63) / 64;  // 1563
  const int AB = (N + 3) / 4;    // 25000 (4 waves/block, 1 wave per node)

  // layer 1
  gemm_k<128, false><<<GB, 256, 0, stream>>>(x, W1, nullptr, nullptr, dinv, y, N);
  agg128_k<<<AB, 256, 0, stream>>>(y, csr, rowst, deg, dinv, b1, hpre, N);
  stats_partial_k<<<256, 256, 0, stream>>>(hpre, ps, pss, N);
  stats_final_k<<<1, 128, 0, stream>>>(ps, pss, g1, be1, scl, shf, N);
  // layer 2
  gemm_k<128, true><<<GB, 256, 0, stream>>>(hpre, W2, scl, shf, dinv, y, N);
  agg128_k<<<AB, 256, 0, stream>>>(y, csr, rowst, deg, dinv, b2, hpre, N);
  stats_partial_k<<<256, 256, 0, stream>>>(hpre, ps, pss, N);
  stats_final_k<<<1, 128, 0, stream>>>(ps, pss, g2, be2, scl, shf, N);
  // layer 3 + log_softmax
  gemm_k<40, true><<<GB, 256, 0, stream>>>(hpre, W3, scl, shf, dinv, y, N);
  agg40_lsm_k<<<AB, 256, 0, stream>>>(y, csr, rowst, deg, dinv, b3, outp, N);
}

// Round 2
// 907.350 us; speedup vs baseline: 1.0964x; 1.0964x over previous
//
#include <hip/hip_runtime.h>
#include <hip/hip_bf16.h>
#include <math.h>

#define NNODES 100000
#define EPSV 1e-5f
#define NB 196          // ceil(100000/512) coarse buckets of 512 nodes
#define PB_DEPTH 16     // LDS bin depth (16 x int2 = 128B flush)

// ---------------- graph prep ----------------

__global__ __launch_bounds__(256) void zero_i32_k(int* __restrict__ p, int n) {
  int i = blockIdx.x * 256 + threadIdx.x;
  if (i < n) p[i] = 0;
}

// coarse bucket histogram via per-block LDS hist
__global__ __launch_bounds__(256) void bhist_k(const int* __restrict__ ei, int E,
                                               int* __restrict__ bhist) {
  __shared__ int lh[NB];
  for (int i = threadIdx.x; i < NB; i += 256) lh[i] = 0;
  __syncthreads();
  for (int e = blockIdx.x * 256 + threadIdx.x; e < E; e += gridDim.x * 256)
    atomicAdd(&lh[ei[E + e] >> 9], 1);
  __syncthreads();
  for (int i = threadIdx.x; i < NB; i += 256)
    if (lh[i]) atomicAdd(&bhist[i], lh[i]);
}

// exclusive scan of NB bucket counts (single block)
__global__ __launch_bounds__(256) void scan_boff_k(const int* __restrict__ bhist,
                                                   int* __restrict__ boff, int E) {
  __shared__ int sm[256];
  int v = (threadIdx.x < NB) ? bhist[threadIdx.x] : 0;
  sm[threadIdx.x] = v;
  __syncthreads();
  for (int off = 1; off < 256; off <<= 1) {
    int t = (threadIdx.x >= off) ? sm[threadIdx.x - off] : 0;
    __syncthreads();
    sm[threadIdx.x] += t;
    __syncthreads();
  }
  if (threadIdx.x < NB) boff[threadIdx.x] = sm[threadIdx.x] - v;
  if (threadIdx.x == 0) boff[NB] = E;
}

// LDS-binned partition: edges -> ebuf grouped by coarse bucket, full-line flushes
__global__ __launch_bounds__(256) void partition_k(const int* __restrict__ ei, int E,
                                                   const int* __restrict__ boff,
                                                   int* __restrict__ gcur,
                                                   int2* __restrict__ ebuf) {
  __shared__ int2 bin[NB][PB_DEPTH];
  __shared__ int lcnt[NB];
  for (int i = threadIdx.x; i < NB; i += 256) lcnt[i] = 0;
  __syncthreads();
  int nchunk = (E + 255) >> 8;
  for (int c = blockIdx.x; c < nchunk; c += gridDim.x) {
    int e = c * 256 + threadIdx.x;
    bool active = (e < E);
    int s = 0, d = 0, b = 0;
    if (active) { s = ei[e]; d = ei[E + e]; b = d >> 9; }
    while (true) {
      if (active) {
        int p = atomicAdd(&lcnt[b], 1);
        if (p < PB_DEPTH) { bin[b][p] = make_int2(s, d); active = false; }
      }
      __syncthreads();
      if (threadIdx.x < NB) {
        int cn = lcnt[threadIdx.x];
        if (cn >= PB_DEPTH) {
          int base = atomicAdd(&gcur[threadIdx.x], PB_DEPTH);
          int2* dst = &ebuf[boff[threadIdx.x] + base];
#pragma unroll
          for (int j = 0; j < PB_DEPTH; ++j) dst[j] = bin[threadIdx.x][j];
        }
      }
      __syncthreads();
      if (threadIdx.x < NB && lcnt[threadIdx.x] >= PB_DEPTH) lcnt[threadIdx.x] = 0;
      if (__syncthreads_count(active ? 1 : 0) == 0) break;
    }
  }
  // tail flush of partial bins
  if (threadIdx.x < NB) {
    int cn = lcnt[threadIdx.x];
    if (cn > 0) {
      int base = atomicAdd(&gcur[threadIdx.x], cn);
      int2* dst = &ebuf[boff[threadIdx.x] + base];
      for (int j = 0; j < cn; ++j) dst[j] = bin[threadIdx.x][j];
    }
  }
}

// per-bucket node-degree histogram (LDS), coalesced deg writes
__global__ __launch_bounds__(256) void histnode_k(const int2* __restrict__ ebuf,
                                                  const int* __restrict__ boff,
                                                  int* __restrict__ deg, int n) {
  __shared__ int h[512];
  int b = blockIdx.x;
  for (int i = threadIdx.x; i < 512; i += 256) h[i] = 0;
  __syncthreads();
  int s0 = boff[b], s1 = boff[b + 1];
  for (int i = s0 + threadIdx.x; i < s1; i += 256)
    atomicAdd(&h[ebuf[i].y & 511], 1);
  __syncthreads();
  int nb0 = b * 512;
  for (int i = threadIdx.x; i < 512; i += 256)
    if (nb0 + i < n) deg[nb0 + i] = h[i];
}

// inclusive scan of 256-chunks; rowst gets inclusive values, chunk gets totals
__global__ __launch_bounds__(256) void scanA_k(const int* __restrict__ cnt, int* __restrict__ rowst,
                                               int* __restrict__ chunk, int n) {
  __shared__ int sm[256];
  int i = blockIdx.x * 256 + threadIdx.x;
  int v = (i < n) ? cnt[i] : 0;
  sm[threadIdx.x] = v;
  __syncthreads();
  for (int off = 1; off < 256; off <<= 1) {
    int t = (threadIdx.x >= off) ? sm[threadIdx.x - off] : 0;
    __syncthreads();
    sm[threadIdx.x] += t;
    __syncthreads();
  }
  if (i < n) rowst[i] = sm[threadIdx.x];
  if (threadIdx.x == 255) chunk[blockIdx.x] = sm[255];
}

__global__ __launch_bounds__(512) void scanB_k(int* __restrict__ chunk, int nc) {
  __shared__ int sm[512];
  int v = (threadIdx.x < nc) ? chunk[threadIdx.x] : 0;
  sm[threadIdx.x] = v;
  __syncthreads();
  for (int off = 1; off < 512; off <<= 1) {
    int t = (threadIdx.x >= off) ? sm[threadIdx.x - off] : 0;
    __syncthreads();
    sm[threadIdx.x] += t;
    __syncthreads();
  }
  if (threadIdx.x < nc) chunk[threadIdx.x] = sm[threadIdx.x] - v;
}

__global__ __launch_bounds__(256) void scanC_k(const int* __restrict__ cnt, const int* __restrict__ chunk,
                                               int* __restrict__ rowst, int n) {
  int i = blockIdx.x * 256 + threadIdx.x;
  if (i < n) rowst[i] = chunk[blockIdx.x] + rowst[i] - cnt[i];
}

__global__ __launch_bounds__(256) void dinv_k(const int* __restrict__ deg, float* __restrict__ dinv, int n) {
  int i = blockIdx.x * 256 + threadIdx.x;
  if (i < n) dinv[i] = rsqrtf((float)deg[i] + 1.0f);
}

// per-bucket fine fill: CSR window (~32KB) written by one workgroup, LDS cursors
__global__ __launch_bounds__(256) void fillB_k(const int2* __restrict__ ebuf,
                                               const int* __restrict__ boff,
                                               const int* __restrict__ rowst,
                                               int* __restrict__ csr, int n, int E) {
  __shared__ int rst[512];
  __shared__ int cur[512];
  int b = blockIdx.x;
  int nb0 = b * 512;
  for (int i = threadIdx.x; i < 512; i += 256) {
    int node = nb0 + i;
    rst[i] = (node < n) ? rowst[node] : E;
    cur[i] = 0;
  }
  __syncthreads();
  int s0 = boff[b], s1 = boff[b + 1];
  for (int i = s0 + threadIdx.x; i < s1; i += 256) {
    int2 e = ebuf[i];
    int l = e.y & 511;
    int p = atomicAdd(&cur[l], 1);
    csr[rst[l] + p] = e.x;
  }
}

// ---------------- GEMM: y[r][c] = dinv[r] * sum_k z[r][k] * W[k][c] ----------------
// z = BN ? relu(in*scale + shift) : in.   BM=64, K=128 fixed.

template <int NOUT, bool BN>
__global__ __launch_bounds__(256) void gemm_k(const float* __restrict__ in, const float* __restrict__ W,
                                              const float* __restrict__ scale, const float* __restrict__ shift,
                                              const float* __restrict__ dinv, float* __restrict__ y, int n) {
  __shared__ float zs[64][132];
  __shared__ float wsm[128 * NOUT];
  const int tid = threadIdx.x;
  const int row0 = blockIdx.x * 64;

  for (int f = tid * 4; f < 128 * NOUT; f += 1024)
    *(float4*)&wsm[f] = *(const float4*)&W[f];

#pragma unroll
  for (int it = 0; it < 8; ++it) {
    int f = tid + it * 256;
    int r = f >> 5, c4 = (f & 31) * 4;
    int row = row0 + r;
    float4 v;
    if (row < n) v = *(const float4*)&in[(size_t)row * 128 + c4];
    else v = make_float4(0.f, 0.f, 0.f, 0.f);
    if (BN) {
      float4 sc = *(const float4*)&scale[c4];
      float4 sh = *(const float4*)&shift[c4];
      v.x = fmaxf(fmaf(v.x, sc.x, sh.x), 0.f);
      v.y = fmaxf(fmaf(v.y, sc.y, sh.y), 0.f);
      v.z = fmaxf(fmaf(v.z, sc.z, sh.z), 0.f);
      v.w = fmaxf(fmaf(v.w, sc.w, sh.w), 0.f);
    }
    *(float4*)&zs[r][c4] = v;
  }
  __syncthreads();

  if constexpr (NOUT == 128) {
    const int tr = tid >> 4, tc = tid & 15;
    const int r0 = tr * 4, c0 = tc * 8;
    float acc[4][8];
#pragma unroll
    for (int i = 0; i < 4; ++i)
#pragma unroll
      for (int j = 0; j < 8; ++j) acc[i][j] = 0.f;

#pragma unroll 4
    for (int k = 0; k < 128; ++k) {
      float a[4];
#pragma unroll
      for (int i = 0; i < 4; ++i) a[i] = zs[r0 + i][k];
      float4 b0 = *(const float4*)&wsm[k * 128 + c0];
      float4 b1 = *(const float4*)&wsm[k * 128 + c0 + 4];
#pragma unroll
      for (int i = 0; i < 4; ++i) {
        acc[i][0] = fmaf(a[i], b0.x, acc[i][0]);
        acc[i][1] = fmaf(a[i], b0.y, acc[i][1]);
        acc[i][2] = fmaf(a[i], b0.z, acc[i][2]);
        acc[i][3] = fmaf(a[i], b0.w, acc[i][3]);
        acc[i][4] = fmaf(a[i], b1.x, acc[i][4]);
        acc[i][5] = fmaf(a[i], b1.y, acc[i][5]);
        acc[i][6] = fmaf(a[i], b1.z, acc[i][6]);
        acc[i][7] = fmaf(a[i], b1.w, acc[i][7]);
      }
    }
#pragma unroll
    for (int i = 0; i < 4; ++i) {
      int row = row0 + r0 + i;
      if (row < n) {
        float dv = dinv[row];
        float4 o0, o1;
        o0.x = acc[i][0] * dv; o0.y = acc[i][1] * dv; o0.z = acc[i][2] * dv; o0.w = acc[i][3] * dv;
        o1.x = acc[i][4] * dv; o1.y = acc[i][5] * dv; o1.z = acc[i][6] * dv; o1.w = acc[i][7] * dv;
        *(float4*)&y[(size_t)row * 128 + c0] = o0;
        *(float4*)&y[(size_t)row * 128 + c0 + 4] = o1;
      }
    }
  } else {  // NOUT == 40
    const int r = tid >> 2;
    const int c0 = (tid & 3) * 10;
    float acc[10];
#pragma unroll
    for (int j = 0; j < 10; ++j) acc[j] = 0.f;
#pragma unroll 4
    for (int k = 0; k < 128; ++k) {
      float a = zs[r][k];
#pragma unroll
      for (int j = 0; j < 10; ++j) acc[j] = fmaf(a, wsm[k * NOUT + c0 + j], acc[j]);
    }
    int row = row0 + r;
    if (row < n) {
      float dv = dinv[row];
#pragma unroll
      for (int j = 0; j < 10; ++j) y[(size_t)row * NOUT + c0 + j] = acc[j] * dv;
    }
  }
}

// ---------------- aggregation ----------------

__global__ __launch_bounds__(256) void agg128_k(const float* __restrict__ y, const int* __restrict__ csr,
                                                const int* __restrict__ rowst, const int* __restrict__ deg,
                                                const float* __restrict__ dinv, const float* __restrict__ bias,
                                                float* __restrict__ out, int n) {
  int wid = (blockIdx.x * 256 + threadIdx.x) >> 6;
  if (wid >= n) return;
  int lane = threadIdx.x & 63;
  int base = rowst[wid];
  int dg = deg[wid];
  size_t co = (size_t)(lane * 2);
  float a0 = 0.f, a1 = 0.f, b0 = 0.f, b1 = 0.f, c0 = 0.f, c1 = 0.f, d0 = 0.f, d1 = 0.f;
  int t = 0;
  for (; t + 4 <= dg; t += 4) {
    int s0 = csr[base + t], s1 = csr[base + t + 1], s2 = csr[base + t + 2], s3 = csr[base + t + 3];
    float2 v0 = *(const float2*)&y[(size_t)s0 * 128 + co];
    float2 v1 = *(const float2*)&y[(size_t)s1 * 128 + co];
    float2 v2 = *(const float2*)&y[(size_t)s2 * 128 + co];
    float2 v3 = *(const float2*)&y[(size_t)s3 * 128 + co];
    a0 += v0.x; a1 += v0.y; b0 += v1.x; b1 += v1.y;
    c0 += v2.x; c1 += v2.y; d0 += v3.x; d1 += v3.y;
  }
  for (; t < dg; ++t) {
    int s = csr[base + t];
    float2 v = *(const float2*)&y[(size_t)s * 128 + co];
    a0 += v.x; a1 += v.y;
  }
  float2 vs = *(const float2*)&y[(size_t)wid * 128 + co];
  a0 += vs.x; a1 += vs.y;
  float s0 = (a0 + b0) + (c0 + d0);
  float s1 = (a1 + b1) + (c1 + d1);
  float dv = dinv[wid];
  float2 bb = *(const float2*)&bias[lane * 2];
  float2 o;
  o.x = fmaf(s0, dv, bb.x);
  o.y = fmaf(s1, dv, bb.y);
  *(float2*)&out[(size_t)wid * 128 + co] = o;
}

__global__ __launch_bounds__(256) void agg40_lsm_k(const float* __restrict__ y, const int* __restrict__ csr,
                                                   const int* __restrict__ rowst, const int* __restrict__ deg,
                                                   const float* __restrict__ dinv, const float* __restrict__ bias,
                                                   float* __restrict__ out, int n) {
  int wid = (blockIdx.x * 256 + threadIdx.x) >> 6;
  if (wid >= n) return;
  int lane = threadIdx.x & 63;
  int col = lane < 40 ? lane : 39;
  int base = rowst[wid];
  int dg = deg[wid];
  float a = 0.f, b = 0.f, c = 0.f, d = 0.f;
  int t = 0;
  for (; t + 4 <= dg; t += 4) {
    int s0 = csr[base + t], s1 = csr[base + t + 1], s2 = csr[base + t + 2], s3 = csr[base + t + 3];
    a += y[(size_t)s0 * 40 + col];
    b += y[(size_t)s1 * 40 + col];
    c += y[(size_t)s2 * 40 + col];
    d += y[(size_t)s3 * 40 + col];
  }
  for (; t < dg; ++t) {
    int s = csr[base + t];
    a += y[(size_t)s * 40 + col];
  }
  a += y[(size_t)wid * 40 + col];
  float v = fmaf((a + b) + (c + d), dinv[wid], bias[col]);
  bool act = lane < 40;
  float m = act ? v : -INFINITY;
#pragma unroll
  for (int off = 32; off; off >>= 1) m = fmaxf(m, __shfl_xor(m, off));
  float e = act ? expf(v - m) : 0.f;
  float se = e;
#pragma unroll
  for (int off = 32; off; off >>= 1) se += __shfl_xor(se, off);
  if (act) out[(size_t)wid * 40 + lane] = v - m - logf(se);
}

// ---------------- BN stats ----------------

__global__ __launch_bounds__(256) void stats_partial_k(const float* __restrict__ h,
                                                       float* __restrict__ ps, float* __restrict__ pss, int n) {
  int c = threadIdx.x & 127;
  int half = threadIdx.x >> 7;
  int r0 = blockIdx.x * 2 + half;
  float s = 0.f, ss = 0.f;
  for (int r = r0; r < n; r += 512) {
    float v = h[(size_t)r * 128 + c];
    s += v;
    ss = fmaf(v, v, ss);
  }
  __shared__ float sm[256], sm2[256];
  sm[threadIdx.x] = s;
  sm2[threadIdx.x] = ss;
  __syncthreads();
  if (threadIdx.x < 128) {
    ps[blockIdx.x * 128 + c] = sm[c] + sm[c + 128];
    pss[blockIdx.x * 128 + c] = sm2[c] + sm2[c + 128];
  }
}

__global__ __launch_bounds__(128) void stats_final_k(const float* __restrict__ ps, const float* __restrict__ pss,
                                                     const float* __restrict__ g, const float* __restrict__ be,
                                                     float* __restrict__ scale, float* __restrict__ shift, int n) {
  int c = threadIdx.x;
  float s = 0.f, ss = 0.f;
  for (int b = 0; b < 256; ++b) {
    s += ps[b * 128 + c];
    ss += pss[b * 128 + c];
  }
  float mu = s / (float)n;
  float var = ss / (float)n - mu * mu;
  float rs = rsqrtf(var + EPSV);
  float sc = rs * g[c];
  scale[c] = sc;
  shift[c] = fmaf(-mu, sc, be[c]);
}

// ---------------- launch ----------------

extern "C" void kernel_launch(void* const* d_in, const int* in_sizes, int n_in,
                              void* d_out, int out_size, void* d_ws, size_t ws_size,
                              hipStream_t stream) {
  const float* x   = (const float*)d_in[0];
  const int*   ei  = (const int*)d_in[1];
  const float* W1  = (const float*)d_in[2];
  const float* b1  = (const float*)d_in[3];
  const float* W2  = (const float*)d_in[4];
  const float* b2  = (const float*)d_in[5];
  const float* W3  = (const float*)d_in[6];
  const float* b3  = (const float*)d_in[7];
  const float* g1  = (const float*)d_in[8];
  const float* be1 = (const float*)d_in[9];
  const float* g2  = (const float*)d_in[10];
  const float* be2 = (const float*)d_in[11];
  float* outp = (float*)d_out;

  const int N = NNODES;
  const int E = in_sizes[1] / 2;
  const int NC = (N + 255) / 256;  // 391

  char* w = (char*)d_ws;
  auto alloc = [&](size_t bytes) -> void* {
    void* p = (void*)w;
    w += (bytes + 255) & ~(size_t)255;
    return p;
  };
  int*   deg    = (int*)alloc((size_t)N * 4);
  int*   rowst  = (int*)alloc((size_t)N * 4);
  int*   chunk  = (int*)alloc((size_t)(NC + 1) * 4);
  int*   csr    = (int*)alloc((size_t)E * 4);
  float* dinv   = (float*)alloc((size_t)N * 4);
  float* y      = (float*)alloc((size_t)N * 128 * 4);
  float* hpre   = (float*)alloc((size_t)N * 128 * 4);
  float* ps     = (float*)alloc((size_t)256 * 128 * 4);
  float* pss    = (float*)alloc((size_t)256 * 128 * 4);
  float* scl    = (float*)alloc(128 * 4);
  float* shf    = (float*)alloc(128 * 4);
  int*   bhist  = (int*)alloc((size_t)(2 * NB + 4) * 4);  // bhist[NB] then gcur[NB]
  int*   gcur   = bhist + NB;
  int*   boff   = (int*)alloc((size_t)(NB + 1) * 4);
  int2*  ebuf   = (int2*)hpre;  // alias: prep finishes before hpre is written

  // graph prep (bucketed counting sort; no random-scatter lines)
  zero_i32_k<<<(2 * NB + 255) / 256, 256, 0, stream>>>(bhist, 2 * NB);
  bhist_k<<<512, 256, 0, stream>>>(ei, E, bhist);
  scan_boff_k<<<1, 256, 0, stream>>>(bhist, boff, E);
  partition_k<<<256, 256, 0, stream>>>(ei, E, boff, gcur, ebuf);
  histnode_k<<<NB, 256, 0, stream>>>(ebuf, boff, deg, N);
  scanA_k<<<NC, 256, 0, stream>>>(deg, rowst, chunk, N);
  scanB_k<<<1, 512, 0, stream>>>(chunk, NC);
  scanC_k<<<NC, 256, 0, stream>>>(deg, chunk, rowst, N);
  dinv_k<<<(N + 255) / 256, 256, 0, stream>>>(deg, dinv, N);
  fillB_k<<<NB, 256, 0, stream>>>(ebuf, boff, rowst, csr, N, E);

  const int GB = (N + 63) / 64;  // 1563
  const int AB = (N + 3) / 4;    // 25000

  // layer 1
  gemm_k<128, false><<<GB, 256, 0, stream>>>(x, W1, nullptr, nullptr, dinv, y, N);
  agg128_k<<<AB, 256, 0, stream>>>(y, csr, rowst, deg, dinv, b1, hpre, N);
  stats_partial_k<<<256, 256, 0, stream>>>(hpre, ps, pss, N);
  stats_final_k<<<1, 128, 0, stream>>>(ps, pss, g1, be1, scl, shf, N);
  // layer 2
  gemm_k<128, true><<<GB, 256, 0, stream>>>(hpre, W2, scl, shf, dinv, y, N);
  agg128_k<<<AB, 256, 0, stream>>>(y, csr, rowst, deg, dinv, b2, hpre, N);
  stats_partial_k<<<256, 256, 0, stream>>>(hpre, ps, pss, N);
  stats_final_k<<<1, 128, 0, stream>>>(ps, pss, g2, be2, scl, shf, N);
  // layer 3 + log_softmax
  gemm_k<40, true><<<GB, 256, 0, stream>>>(hpre, W3, scl, shf, dinv, y, N);
  agg40_lsm_k<<<AB, 256, 0, stream>>>(y, csr, rowst, deg, dinv, b3, outp, N);
}

// Round 3
// 668.186 us; speedup vs baseline: 1.4888x; 1.3579x over previous
//
#include <hip/hip_runtime.h>
#include <hip/hip_bf16.h>
#include <math.h>

#define NNODES 100000
#define EPSV 1e-5f
#define NB 196          // ceil(100000/512) coarse buckets of 512 nodes
#define PB_DEPTH 16     // LDS bin depth (16 x int2 = 128B flush)

typedef __attribute__((ext_vector_type(8))) short short8v;   // 8 bf16 = 4 VGPR
typedef __attribute__((ext_vector_type(4))) float f32x4;

__device__ __forceinline__ ushort f2bf(float f) {
  uint u = __float_as_uint(f);
  return (ushort)((u + 0x7fffu + ((u >> 16) & 1u)) >> 16);  // RNE
}
__device__ __forceinline__ float bf2f(ushort h) { return __uint_as_float(((uint)h) << 16); }

// swizzled LDS offset for tiles with 256B rows: XOR 16B-granule index with row&7
__device__ __forceinline__ int lds_off(int row, int byteInRow) {
  return row * 256 + ((((byteInRow >> 4) ^ (row & 7)) << 4) | (byteInRow & 15));
}

// ---------------- graph prep ----------------

__global__ __launch_bounds__(256) void zero_i32_k(int* __restrict__ p, int n) {
  int i = blockIdx.x * 256 + threadIdx.x;
  if (i < n) p[i] = 0;
}

__global__ __launch_bounds__(256) void bhist_k(const int* __restrict__ ei, int E,
                                               int* __restrict__ bhist) {
  __shared__ int lh[NB];
  for (int i = threadIdx.x; i < NB; i += 256) lh[i] = 0;
  __syncthreads();
  for (int e = blockIdx.x * 256 + threadIdx.x; e < E; e += gridDim.x * 256)
    atomicAdd(&lh[ei[E + e] >> 9], 1);
  __syncthreads();
  for (int i = threadIdx.x; i < NB; i += 256)
    if (lh[i]) atomicAdd(&bhist[i], lh[i]);
}

__global__ __launch_bounds__(256) void scan_boff_k(const int* __restrict__ bhist,
                                                   int* __restrict__ boff, int E) {
  __shared__ int sm[256];
  int v = (threadIdx.x < NB) ? bhist[threadIdx.x] : 0;
  sm[threadIdx.x] = v;
  __syncthreads();
  for (int off = 1; off < 256; off <<= 1) {
    int t = (threadIdx.x >= off) ? sm[threadIdx.x - off] : 0;
    __syncthreads();
    sm[threadIdx.x] += t;
    __syncthreads();
  }
  if (threadIdx.x < NB) boff[threadIdx.x] = sm[threadIdx.x] - v;
  if (threadIdx.x == 0) boff[NB] = E;
}

__global__ __launch_bounds__(256) void partition_k(const int* __restrict__ ei, int E,
                                                   const int* __restrict__ boff,
                                                   int* __restrict__ gcur,
                                                   int2* __restrict__ ebuf) {
  __shared__ int2 bin[NB][PB_DEPTH];
  __shared__ int lcnt[NB];
  for (int i = threadIdx.x; i < NB; i += 256) lcnt[i] = 0;
  __syncthreads();
  int nchunk = (E + 255) >> 8;
  for (int c = blockIdx.x; c < nchunk; c += gridDim.x) {
    int e = c * 256 + threadIdx.x;
    bool active = (e < E);
    int s = 0, d = 0, b = 0;
    if (active) { s = ei[e]; d = ei[E + e]; b = d >> 9; }
    while (true) {
      if (active) {
        int p = atomicAdd(&lcnt[b], 1);
        if (p < PB_DEPTH) { bin[b][p] = make_int2(s, d); active = false; }
      }
      __syncthreads();
      if (threadIdx.x < NB) {
        int cn = lcnt[threadIdx.x];
        if (cn >= PB_DEPTH) {
          int base = atomicAdd(&gcur[threadIdx.x], PB_DEPTH);
          int2* dst = &ebuf[boff[threadIdx.x] + base];
#pragma unroll
          for (int j = 0; j < PB_DEPTH; ++j) dst[j] = bin[threadIdx.x][j];
        }
      }
      __syncthreads();
      if (threadIdx.x < NB && lcnt[threadIdx.x] >= PB_DEPTH) lcnt[threadIdx.x] = 0;
      if (__syncthreads_count(active ? 1 : 0) == 0) break;
    }
  }
  if (threadIdx.x < NB) {
    int cn = lcnt[threadIdx.x];
    if (cn > 0) {
      int base = atomicAdd(&gcur[threadIdx.x], cn);
      int2* dst = &ebuf[boff[threadIdx.x] + base];
      for (int j = 0; j < cn; ++j) dst[j] = bin[threadIdx.x][j];
    }
  }
}

__global__ __launch_bounds__(256) void histnode_k(const int2* __restrict__ ebuf,
                                                  const int* __restrict__ boff,
                                                  int* __restrict__ deg, int n) {
  __shared__ int h[512];
  int b = blockIdx.x;
  for (int i = threadIdx.x; i < 512; i += 256) h[i] = 0;
  __syncthreads();
  int s0 = boff[b], s1 = boff[b + 1];
  for (int i = s0 + threadIdx.x; i < s1; i += 256)
    atomicAdd(&h[ebuf[i].y & 511], 1);
  __syncthreads();
  int nb0 = b * 512;
  for (int i = threadIdx.x; i < 512; i += 256)
    if (nb0 + i < n) deg[nb0 + i] = h[i];
}

__global__ __launch_bounds__(256) void scanA_k(const int* __restrict__ cnt, int* __restrict__ rowst,
                                               int* __restrict__ chunk, int n) {
  __shared__ int sm[256];
  int i = blockIdx.x * 256 + threadIdx.x;
  int v = (i < n) ? cnt[i] : 0;
  sm[threadIdx.x] = v;
  __syncthreads();
  for (int off = 1; off < 256; off <<= 1) {
    int t = (threadIdx.x >= off) ? sm[threadIdx.x - off] : 0;
    __syncthreads();
    sm[threadIdx.x] += t;
    __syncthreads();
  }
  if (i < n) rowst[i] = sm[threadIdx.x];
  if (threadIdx.x == 255) chunk[blockIdx.x] = sm[255];
}

__global__ __launch_bounds__(512) void scanB_k(int* __restrict__ chunk, int nc) {
  __shared__ int sm[512];
  int v = (threadIdx.x < nc) ? chunk[threadIdx.x] : 0;
  sm[threadIdx.x] = v;
  __syncthreads();
  for (int off = 1; off < 512; off <<= 1) {
    int t = (threadIdx.x >= off) ? sm[threadIdx.x - off] : 0;
    __syncthreads();
    sm[threadIdx.x] += t;
    __syncthreads();
  }
  if (threadIdx.x < nc) chunk[threadIdx.x] = sm[threadIdx.x] - v;
}

__global__ __launch_bounds__(256) void scanC_k(const int* __restrict__ cnt, const int* __restrict__ chunk,
                                               int* __restrict__ rowst, int n) {
  int i = blockIdx.x * 256 + threadIdx.x;
  if (i < n) rowst[i] = chunk[blockIdx.x] + rowst[i] - cnt[i];
}

__global__ __launch_bounds__(256) void dinv_k(const int* __restrict__ deg, float* __restrict__ dinv, int n) {
  int i = blockIdx.x * 256 + threadIdx.x;
  if (i < n) dinv[i] = rsqrtf((float)deg[i] + 1.0f);
}

__global__ __launch_bounds__(256) void fillB_k(const int2* __restrict__ ebuf,
                                               const int* __restrict__ boff,
                                               const int* __restrict__ rowst,
                                               int* __restrict__ csr, int n, int E) {
  __shared__ int rst[512];
  __shared__ int cur[512];
  int b = blockIdx.x;
  int nb0 = b * 512;
  for (int i = threadIdx.x; i < 512; i += 256) {
    int node = nb0 + i;
    rst[i] = (node < n) ? rowst[node] : E;
    cur[i] = 0;
  }
  __syncthreads();
  int s0 = boff[b], s1 = boff[b + 1];
  for (int i = s0 + threadIdx.x; i < s1; i += 256) {
    int2 e = ebuf[i];
    int l = e.y & 511;
    int p = atomicAdd(&cur[l], 1);
    csr[rst[l] + p] = e.x;
  }
}

// ---------------- MFMA GEMM: y_bf16[r][c] = dinv[r] * sum_k z[r][k] * W[k][c] ----------------
// z = BN ? relu(in*scale+shift) : in.  64 rows/block, 4 waves, each wave 16 rows x NOUT cols.

template <int NREAL, bool BN>  // NREAL = 128 or 40
__global__ __launch_bounds__(256) void gemm_mfma_k(const float* __restrict__ in, const float* __restrict__ W,
                                                   const float* __restrict__ scale, const float* __restrict__ shift,
                                                   const float* __restrict__ dinv, ushort* __restrict__ y, int n) {
  constexpr int NT = (NREAL + 15) / 16;  // col tiles: 8 or 3
  __shared__ ushort At[64 * 128];        // swizzled A tile; reused as output tile
  __shared__ ushort Wt[NT * 16 * 128];   // swizzled W^T (col-major: [col][k])
  const int tid = threadIdx.x;
  const int row0 = blockIdx.x * 64;

  // zero the padded cols (NREAL=40 -> cols 40..47)
  if constexpr (NREAL != NT * 16) {
    for (int i = tid; i < (NT * 16 - NREAL) * 128; i += 256) {
      int c = NREAL + (i >> 7), k = i & 127;
      *(ushort*)((char*)Wt + lds_off(c, k * 2)) = 0;
    }
  }
  // stage W^T (cvt to bf16)
  for (int e = tid * 4; e < 128 * NREAL; e += 1024) {
    float4 w4 = *(const float4*)&W[e];
    int k = e / NREAL, c = e % NREAL;
    const float* wp = (const float*)&w4;
#pragma unroll
    for (int j = 0; j < 4; ++j)
      *(ushort*)((char*)Wt + lds_off(c + j, k * 2)) = f2bf(wp[j]);
  }

  // stage A tile: BN+ReLU fused, cvt bf16
#pragma unroll
  for (int it = 0; it < 8; ++it) {
    int f = tid + it * 256;          // 0..2047 float4 ids
    int r = f >> 5, c4 = (f & 31) * 4;
    int row = row0 + r;
    float4 v;
    if (row < n) v = *(const float4*)&in[(size_t)row * 128 + c4];
    else v = make_float4(0.f, 0.f, 0.f, 0.f);
    if (BN) {
      float4 sc = *(const float4*)&scale[c4];
      float4 sh = *(const float4*)&shift[c4];
      v.x = fmaxf(fmaf(v.x, sc.x, sh.x), 0.f);
      v.y = fmaxf(fmaf(v.y, sc.y, sh.y), 0.f);
      v.z = fmaxf(fmaf(v.z, sc.z, sh.z), 0.f);
      v.w = fmaxf(fmaf(v.w, sc.w, sh.w), 0.f);
    }
    ushort4 h;
    h.x = f2bf(v.x); h.y = f2bf(v.y); h.z = f2bf(v.z); h.w = f2bf(v.w);
    *(ushort4*)((char*)At + lds_off(r, c4 * 2)) = h;
  }
  __syncthreads();

  const int w = tid >> 6, lane = tid & 63;
  const int lr = lane & 15, g = lane >> 4;

  // A fragments for this wave's 16 rows (K=128 -> 4 mfma steps)
  short8v a[4];
#pragma unroll
  for (int kk = 0; kk < 4; ++kk)
    a[kk] = *(const short8v*)((const char*)At + lds_off(w * 16 + lr, kk * 64 + g * 16));
  float dv[4];
#pragma unroll
  for (int i = 0; i < 4; ++i) {
    int rr = row0 + w * 16 + g * 4 + i;
    dv[i] = (rr < n) ? dinv[rr] : 0.f;
  }
  __syncthreads();  // all waves done reading At -> reuse as output tile

#pragma unroll
  for (int ct = 0; ct < NT; ++ct) {
    f32x4 acc = {0.f, 0.f, 0.f, 0.f};
#pragma unroll
    for (int kk = 0; kk < 4; ++kk) {
      short8v b = *(const short8v*)((const char*)Wt + lds_off(ct * 16 + lr, kk * 64 + g * 16));
      acc = __builtin_amdgcn_mfma_f32_16x16x32_bf16(a[kk], b, acc, 0, 0, 0);
    }
    // C/D layout: col = lane&15, row = (lane>>4)*4 + i  [verified m89]
#pragma unroll
    for (int i = 0; i < 4; ++i)
      *(ushort*)((char*)At + lds_off(w * 16 + g * 4 + i, (ct * 16 + lr) * 2)) = f2bf(acc[i] * dv[i]);
  }
  __syncthreads();

  // coalesced global write from output tile
  if constexpr (NREAL == 128) {
#pragma unroll
    for (int it = 0; it < 4; ++it) {
      int cid = tid + it * 256;        // 0..1023 (16B chunks)
      int r = cid >> 4, gg = cid & 15;
      int row = row0 + r;
      if (row < n) {
        short8v t = *(const short8v*)((const char*)At + lds_off(r, gg * 16));
        *(short8v*)&y[(size_t)row * 128 + gg * 8] = t;
      }
    }
  } else {
#pragma unroll
    for (int it = 0; it < 3; ++it) {
      int cid = tid + it * 256;        // 0..639 (8B chunks, 10 per row)
      if (cid < 640) {
        int r = cid / 10, u = cid - r * 10;
        int row = row0 + r;
        if (row < n) {
          ushort4 t = *(const ushort4*)((const char*)At + lds_off(r, u * 8));
          *(ushort4*)&y[(size_t)row * 40 + u * 4] = t;
        }
      }
    }
  }
}

// ---------------- aggregation (bf16 y gather, fp32 accumulate) ----------------

__global__ __launch_bounds__(256) void agg128_k(const ushort* __restrict__ y, const int* __restrict__ csr,
                                                const int* __restrict__ rowst, const int* __restrict__ deg,
                                                const float* __restrict__ dinv, const float* __restrict__ bias,
                                                float* __restrict__ out, int n) {
  int wid = (blockIdx.x * 256 + threadIdx.x) >> 6;
  if (wid >= n) return;
  int lane = threadIdx.x & 63;
  int base = rowst[wid];
  int dg = deg[wid];
  const uint* yu = (const uint*)y;      // 64 uints (128 bf16) per row
  float a0 = 0.f, a1 = 0.f, b0 = 0.f, b1 = 0.f, c0 = 0.f, c1 = 0.f, d0 = 0.f, d1 = 0.f;
  int t = 0;
  for (; t + 4 <= dg; t += 4) {
    int s0 = csr[base + t], s1 = csr[base + t + 1], s2 = csr[base + t + 2], s3 = csr[base + t + 3];
    uint v0 = yu[(size_t)s0 * 64 + lane];
    uint v1 = yu[(size_t)s1 * 64 + lane];
    uint v2 = yu[(size_t)s2 * 64 + lane];
    uint v3 = yu[(size_t)s3 * 64 + lane];
    a0 += __uint_as_float(v0 << 16); a1 += __uint_as_float(v0 & 0xffff0000u);
    b0 += __uint_as_float(v1 << 16); b1 += __uint_as_float(v1 & 0xffff0000u);
    c0 += __uint_as_float(v2 << 16); c1 += __uint_as_float(v2 & 0xffff0000u);
    d0 += __uint_as_float(v3 << 16); d1 += __uint_as_float(v3 & 0xffff0000u);
  }
  for (; t < dg; ++t) {
    int s = csr[base + t];
    uint v = yu[(size_t)s * 64 + lane];
    a0 += __uint_as_float(v << 16); a1 += __uint_as_float(v & 0xffff0000u);
  }
  uint vs = yu[(size_t)wid * 64 + lane];
  a0 += __uint_as_float(vs << 16); a1 += __uint_as_float(vs & 0xffff0000u);
  float s0 = (a0 + b0) + (c0 + d0);
  float s1 = (a1 + b1) + (c1 + d1);
  float dvv = dinv[wid];
  float2 bb = *(const float2*)&bias[lane * 2];
  float2 o;
  o.x = fmaf(s0, dvv, bb.x);
  o.y = fmaf(s1, dvv, bb.y);
  *(float2*)&out[(size_t)wid * 128 + lane * 2] = o;
}

__global__ __launch_bounds__(256) void agg40_lsm_k(const ushort* __restrict__ y, const int* __restrict__ csr,
                                                   const int* __restrict__ rowst, const int* __restrict__ deg,
                                                   const float* __restrict__ dinv, const float* __restrict__ bias,
                                                   float* __restrict__ out, int n) {
  int wid = (blockIdx.x * 256 + threadIdx.x) >> 6;
  if (wid >= n) return;
  int lane = threadIdx.x & 63;
  int col = lane < 40 ? lane : 39;
  int base = rowst[wid];
  int dg = deg[wid];
  float a = 0.f, b = 0.f, c = 0.f, d = 0.f;
  int t = 0;
  for (; t + 4 <= dg; t += 4) {
    int s0 = csr[base + t], s1 = csr[base + t + 1], s2 = csr[base + t + 2], s3 = csr[base + t + 3];
    a += bf2f(y[(size_t)s0 * 40 + col]);
    b += bf2f(y[(size_t)s1 * 40 + col]);
    c += bf2f(y[(size_t)s2 * 40 + col]);
    d += bf2f(y[(size_t)s3 * 40 + col]);
  }
  for (; t < dg; ++t) {
    int s = csr[base + t];
    a += bf2f(y[(size_t)s * 40 + col]);
  }
  a += bf2f(y[(size_t)wid * 40 + col]);
  float v = fmaf((a + b) + (c + d), dinv[wid], bias[col]);
  bool act = lane < 40;
  float m = act ? v : -INFINITY;
#pragma unroll
  for (int off = 32; off; off >>= 1) m = fmaxf(m, __shfl_xor(m, off));
  float e = act ? expf(v - m) : 0.f;
  float se = e;
#pragma unroll
  for (int off = 32; off; off >>= 1) se += __shfl_xor(se, off);
  if (act) out[(size_t)wid * 40 + lane] = v - m - logf(se);
}

// ---------------- BN stats ----------------

__global__ __launch_bounds__(256) void stats_partial_k(const float* __restrict__ h,
                                                       float* __restrict__ ps, float* __restrict__ pss, int n) {
  int c = threadIdx.x & 127;
  int half = threadIdx.x >> 7;
  int r0 = blockIdx.x * 2 + half;
  float s = 0.f, ss = 0.f;
  for (int r = r0; r < n; r += 512) {
    float v = h[(size_t)r * 128 + c];
    s += v;
    ss = fmaf(v, v, ss);
  }
  __shared__ float sm[256], sm2[256];
  sm[threadIdx.x] = s;
  sm2[threadIdx.x] = ss;
  __syncthreads();
  if (threadIdx.x < 128) {
    ps[blockIdx.x * 128 + c] = sm[c] + sm[c + 128];
    pss[blockIdx.x * 128 + c] = sm2[c] + sm2[c + 128];
  }
}

__global__ __launch_bounds__(128) void stats_final_k(const float* __restrict__ ps, const float* __restrict__ pss,
                                                     const float* __restrict__ g, const float* __restrict__ be,
                                                     float* __restrict__ scale, float* __restrict__ shift, int n) {
  int c = threadIdx.x;
  float s = 0.f, ss = 0.f;
  for (int b = 0; b < 256; ++b) {
    s += ps[b * 128 + c];
    ss += pss[b * 128 + c];
  }
  float mu = s / (float)n;
  float var = ss / (float)n - mu * mu;
  float rs = rsqrtf(var + EPSV);
  float sc = rs * g[c];
  scale[c] = sc;
  shift[c] = fmaf(-mu, sc, be[c]);
}

// ---------------- launch ----------------

extern "C" void kernel_launch(void* const* d_in, const int* in_sizes, int n_in,
                              void* d_out, int out_size, void* d_ws, size_t ws_size,
                              hipStream_t stream) {
  const float* x   = (const float*)d_in[0];
  const int*   ei  = (const int*)d_in[1];
  const float* W1  = (const float*)d_in[2];
  const float* b1  = (const float*)d_in[3];
  const float* W2  = (const float*)d_in[4];
  const float* b2  = (const float*)d_in[5];
  const float* W3  = (const float*)d_in[6];
  const float* b3  = (const float*)d_in[7];
  const float* g1  = (const float*)d_in[8];
  const float* be1 = (const float*)d_in[9];
  const float* g2  = (const float*)d_in[10];
  const float* be2 = (const float*)d_in[11];
  float* outp = (float*)d_out;

  const int N = NNODES;
  const int E = in_sizes[1] / 2;
  const int NC = (N + 255) / 256;  // 391

  char* w = (char*)d_ws;
  auto alloc = [&](size_t bytes) -> void* {
    void* p = (void*)w;
    w += (bytes + 255) & ~(size_t)255;
    return p;
  };
  int*    deg    = (int*)alloc((size_t)N * 4);
  int*    rowst  = (int*)alloc((size_t)N * 4);
  int*    chunk  = (int*)alloc((size_t)(NC + 1) * 4);
  int*    csr    = (int*)alloc((size_t)E * 4);
  float*  dinv   = (float*)alloc((size_t)N * 4);
  ushort* y      = (ushort*)alloc((size_t)N * 128 * 2);   // bf16 y (layer3 reuses: N*40*2)
  float*  hpre   = (float*)alloc((size_t)N * 128 * 4);
  float*  ps     = (float*)alloc((size_t)256 * 128 * 4);
  float*  pss    = (float*)alloc((size_t)256 * 128 * 4);
  float*  scl    = (float*)alloc(128 * 4);
  float*  shf    = (float*)alloc(128 * 4);
  int*    bhist  = (int*)alloc((size_t)(2 * NB + 4) * 4);
  int*    gcur   = bhist + NB;
  int*    boff   = (int*)alloc((size_t)(NB + 1) * 4);
  int2*   ebuf   = (int2*)hpre;  // alias: prep finishes before hpre is written

  // graph prep (bucketed counting sort)
  zero_i32_k<<<(2 * NB + 255) / 256, 256, 0, stream>>>(bhist, 2 * NB);
  bhist_k<<<512, 256, 0, stream>>>(ei, E, bhist);
  scan_boff_k<<<1, 256, 0, stream>>>(bhist, boff, E);
  partition_k<<<256, 256, 0, stream>>>(ei, E, boff, gcur, ebuf);
  histnode_k<<<NB, 256, 0, stream>>>(ebuf, boff, deg, N);
  scanA_k<<<NC, 256, 0, stream>>>(deg, rowst, chunk, N);
  scanB_k<<<1, 512, 0, stream>>>(chunk, NC);
  scanC_k<<<NC, 256, 0, stream>>>(deg, chunk, rowst, N);
  dinv_k<<<(N + 255) / 256, 256, 0, stream>>>(deg, dinv, N);
  fillB_k<<<NB, 256, 0, stream>>>(ebuf, boff, rowst, csr, N, E);

  const int GB = (N + 63) / 64;  // 1563
  const int AB = (N + 3) / 4;    // 25000

  // layer 1
  gemm_mfma_k<128, false><<<GB, 256, 0, stream>>>(x, W1, nullptr, nullptr, dinv, y, N);
  agg128_k<<<AB, 256, 0, stream>>>(y, csr, rowst, deg, dinv, b1, hpre, N);
  stats_partial_k<<<256, 256, 0, stream>>>(hpre, ps, pss, N);
  stats_final_k<<<1, 128, 0, stream>>>(ps, pss, g1, be1, scl, shf, N);
  // layer 2
  gemm_mfma_k<128, true><<<GB, 256, 0, stream>>>(hpre, W2, scl, shf, dinv, y, N);
  agg128_k<<<AB, 256, 0, stream>>>(y, csr, rowst, deg, dinv, b2, hpre, N);
  stats_partial_k<<<256, 256, 0, stream>>>(hpre, ps, pss, N);
  stats_final_k<<<1, 128, 0, stream>>>(ps, pss, g2, be2, scl, shf, N);
  // layer 3 + log_softmax
  gemm_mfma_k<40, true><<<GB, 256, 0, stream>>>(hpre, W3, scl, shf, dinv, y, N);
  agg40_lsm_k<<<AB, 256, 0, stream>>>(y, csr, rowst, deg, dinv, b3, outp, N);
}

// Round 4
// 607.907 us; speedup vs baseline: 1.6364x; 1.0992x over previous
//
#include <hip/hip_runtime.h>
#include <hip/hip_bf16.h>
#include <math.h>

#define NNODES 100000
#define EPSV 1e-5f
#define NB 196          // ceil(100000/512) coarse buckets of 512 nodes
#define NBLK 256        // partition blocks (fixed; histA/partB must match ranges)

typedef __attribute__((ext_vector_type(8))) short short8v;   // 8 bf16 = 4 VGPR
typedef __attribute__((ext_vector_type(4))) float f32x4;

__device__ __forceinline__ ushort f2bf(float f) {
  uint u = __float_as_uint(f);
  return (ushort)((u + 0x7fffu + ((u >> 16) & 1u)) >> 16);  // RNE
}
__device__ __forceinline__ float bf2f(ushort h) { return __uint_as_float(((uint)h) << 16); }

// swizzled LDS offset for tiles with 256B rows: XOR 16B-granule index with row&7
__device__ __forceinline__ int lds_off(int row, int byteInRow) {
  return row * 256 + ((((byteInRow >> 4) ^ (row & 7)) << 4) | (byteInRow & 15));
}

// ---------------- graph prep: radix partition, no global atomics ----------------

// pass 1: per-block bucket histogram -> hmatT[bucket][block]
__global__ __launch_bounds__(256) void histA_k(const int* __restrict__ ei, int E,
                                               int* __restrict__ hmatT) {
  __shared__ int lh[NB];
  for (int i = threadIdx.x; i < NB; i += 256) lh[i] = 0;
  __syncthreads();
  int per = (E + NBLK - 1) / NBLK;
  int s0 = blockIdx.x * per, s1 = min(E, s0 + per);
  for (int e = s0 + threadIdx.x; e < s1; e += 256)
    atomicAdd(&lh[ei[E + e] >> 9], 1);
  __syncthreads();
  for (int i = threadIdx.x; i < NB; i += 256)
    hmatT[i * NBLK + blockIdx.x] = lh[i];
}

// pass 2 (1 block): bucket totals -> exclusive boff; per-block bases hbaseT
__global__ __launch_bounds__(256) void scanM_k(const int* __restrict__ hmatT,
                                               int* __restrict__ hbaseT,
                                               int* __restrict__ boff, int E) {
  __shared__ int sm[256];
  int tid = threadIdx.x;
  int tot = 0;
  if (tid < NB) {
    const int* rowp = &hmatT[tid * NBLK];
#pragma unroll 8
    for (int b = 0; b < NBLK; ++b) tot += rowp[b];
  }
  sm[tid] = tot;
  __syncthreads();
  for (int off = 1; off < 256; off <<= 1) {
    int t = (tid >= off) ? sm[tid - off] : 0;
    __syncthreads();
    sm[tid] += t;
    __syncthreads();
  }
  if (tid < NB) {
    int run = sm[tid] - tot;     // exclusive
    boff[tid] = run;
    const int* rowp = &hmatT[tid * NBLK];
    int* basep = &hbaseT[tid * NBLK];
    for (int b = 0; b < NBLK; ++b) {
      int c = rowp[b];
      basep[b] = run;
      run += c;
    }
  }
  if (tid == 0) boff[NB] = E;
}

// pass 3: scatter edges to bucket-grouped ebuf via private LDS cursors.
// packed word: (dst & 511) << 17 | src   (src < 2^17)
__global__ __launch_bounds__(256) void partB_k(const int* __restrict__ ei, int E,
                                               const int* __restrict__ hbaseT,
                                               uint* __restrict__ ebuf) {
  __shared__ int cur[NB];
  for (int i = threadIdx.x; i < NB; i += 256)
    cur[i] = hbaseT[i * NBLK + blockIdx.x];
  __syncthreads();
  int per = (E + NBLK - 1) / NBLK;
  int s0 = blockIdx.x * per, s1 = min(E, s0 + per);
  for (int e = s0 + threadIdx.x; e < s1; e += 256) {
    int s = ei[e];
    int d = ei[E + e];
    int p = atomicAdd(&cur[d >> 9], 1);
    ebuf[p] = ((uint)(d & 511) << 17) | (uint)s;
  }
}

// per-bucket node-degree histogram (LDS), coalesced deg writes
__global__ __launch_bounds__(256) void histnode_k(const uint* __restrict__ ebuf,
                                                  const int* __restrict__ boff,
                                                  int* __restrict__ deg, int n) {
  __shared__ int h[512];
  int b = blockIdx.x;
  for (int i = threadIdx.x; i < 512; i += 256) h[i] = 0;
  __syncthreads();
  int s0 = boff[b], s1 = boff[b + 1];
  for (int i = s0 + threadIdx.x; i < s1; i += 256)
    atomicAdd(&h[ebuf[i] >> 17], 1);
  __syncthreads();
  int nb0 = b * 512;
  for (int i = threadIdx.x; i < 512; i += 256)
    if (nb0 + i < n) deg[nb0 + i] = h[i];
}

__global__ __launch_bounds__(256) void scanA_k(const int* __restrict__ cnt, int* __restrict__ rowst,
                                               int* __restrict__ chunk, int n) {
  __shared__ int sm[256];
  int i = blockIdx.x * 256 + threadIdx.x;
  int v = (i < n) ? cnt[i] : 0;
  sm[threadIdx.x] = v;
  __syncthreads();
  for (int off = 1; off < 256; off <<= 1) {
    int t = (threadIdx.x >= off) ? sm[threadIdx.x - off] : 0;
    __syncthreads();
    sm[threadIdx.x] += t;
    __syncthreads();
  }
  if (i < n) rowst[i] = sm[threadIdx.x];
  if (threadIdx.x == 255) chunk[blockIdx.x] = sm[255];
}

__global__ __launch_bounds__(512) void scanB_k(int* __restrict__ chunk, int nc) {
  __shared__ int sm[512];
  int v = (threadIdx.x < nc) ? chunk[threadIdx.x] : 0;
  sm[threadIdx.x] = v;
  __syncthreads();
  for (int off = 1; off < 512; off <<= 1) {
    int t = (threadIdx.x >= off) ? sm[threadIdx.x - off] : 0;
    __syncthreads();
    sm[threadIdx.x] += t;
    __syncthreads();
  }
  if (threadIdx.x < nc) chunk[threadIdx.x] = sm[threadIdx.x] - v;
}

__global__ __launch_bounds__(256) void scanC_k(const int* __restrict__ cnt, const int* __restrict__ chunk,
                                               int* __restrict__ rowst, int n) {
  int i = blockIdx.x * 256 + threadIdx.x;
  if (i < n) rowst[i] = chunk[blockIdx.x] + rowst[i] - cnt[i];
}

__global__ __launch_bounds__(256) void dinv_k(const int* __restrict__ deg, float* __restrict__ dinv, int n) {
  int i = blockIdx.x * 256 + threadIdx.x;
  if (i < n) dinv[i] = rsqrtf((float)deg[i] + 1.0f);
}

// per-bucket fine fill: CSR window written by one workgroup, LDS cursors
__global__ __launch_bounds__(256) void fillB_k(const uint* __restrict__ ebuf,
                                               const int* __restrict__ boff,
                                               const int* __restrict__ rowst,
                                               int* __restrict__ csr, int n, int E) {
  __shared__ int rst[512];
  __shared__ int cur[512];
  int b = blockIdx.x;
  int nb0 = b * 512;
  for (int i = threadIdx.x; i < 512; i += 256) {
    int node = nb0 + i;
    rst[i] = (node < n) ? rowst[node] : E;
    cur[i] = 0;
  }
  __syncthreads();
  int s0 = boff[b], s1 = boff[b + 1];
  for (int i = s0 + threadIdx.x; i < s1; i += 256) {
    uint w = ebuf[i];
    int l = w >> 17;
    int p = atomicAdd(&cur[l], 1);
    csr[rst[l] + p] = (int)(w & 0x1FFFFu);
  }
}

// ---------------- MFMA GEMM: y_bf16[r][c] = dinv[r] * sum_k z[r][k] * W[k][c] ----------------

template <int NREAL, bool BN>  // NREAL = 128 or 40
__global__ __launch_bounds__(256) void gemm_mfma_k(const float* __restrict__ in, const float* __restrict__ W,
                                                   const float* __restrict__ scale, const float* __restrict__ shift,
                                                   const float* __restrict__ dinv, ushort* __restrict__ y, int n) {
  constexpr int NT = (NREAL + 15) / 16;  // col tiles: 8 or 3
  __shared__ ushort At[64 * 128];        // swizzled A tile; reused as output tile
  __shared__ ushort Wt[NT * 16 * 128];   // swizzled W^T (col-major: [col][k])
  const int tid = threadIdx.x;
  const int row0 = blockIdx.x * 64;

  if constexpr (NREAL != NT * 16) {
    for (int i = tid; i < (NT * 16 - NREAL) * 128; i += 256) {
      int c = NREAL + (i >> 7), k = i & 127;
      *(ushort*)((char*)Wt + lds_off(c, k * 2)) = 0;
    }
  }
  for (int e = tid * 4; e < 128 * NREAL; e += 1024) {
    float4 w4 = *(const float4*)&W[e];
    int k = e / NREAL, c = e % NREAL;
    const float* wp = (const float*)&w4;
#pragma unroll
    for (int j = 0; j < 4; ++j)
      *(ushort*)((char*)Wt + lds_off(c + j, k * 2)) = f2bf(wp[j]);
  }

#pragma unroll
  for (int it = 0; it < 8; ++it) {
    int f = tid + it * 256;
    int r = f >> 5, c4 = (f & 31) * 4;
    int row = row0 + r;
    float4 v;
    if (row < n) v = *(const float4*)&in[(size_t)row * 128 + c4];
    else v = make_float4(0.f, 0.f, 0.f, 0.f);
    if (BN) {
      float4 sc = *(const float4*)&scale[c4];
      float4 sh = *(const float4*)&shift[c4];
      v.x = fmaxf(fmaf(v.x, sc.x, sh.x), 0.f);
      v.y = fmaxf(fmaf(v.y, sc.y, sh.y), 0.f);
      v.z = fmaxf(fmaf(v.z, sc.z, sh.z), 0.f);
      v.w = fmaxf(fmaf(v.w, sc.w, sh.w), 0.f);
    }
    ushort4 h;
    h.x = f2bf(v.x); h.y = f2bf(v.y); h.z = f2bf(v.z); h.w = f2bf(v.w);
    *(ushort4*)((char*)At + lds_off(r, c4 * 2)) = h;
  }
  __syncthreads();

  const int w = tid >> 6, lane = tid & 63;
  const int lr = lane & 15, g = lane >> 4;

  short8v a[4];
#pragma unroll
  for (int kk = 0; kk < 4; ++kk)
    a[kk] = *(const short8v*)((const char*)At + lds_off(w * 16 + lr, kk * 64 + g * 16));
  float dv[4];
#pragma unroll
  for (int i = 0; i < 4; ++i) {
    int rr = row0 + w * 16 + g * 4 + i;
    dv[i] = (rr < n) ? dinv[rr] : 0.f;
  }
  __syncthreads();  // all waves done reading At -> reuse as output tile

#pragma unroll
  for (int ct = 0; ct < NT; ++ct) {
    f32x4 acc = {0.f, 0.f, 0.f, 0.f};
#pragma unroll
    for (int kk = 0; kk < 4; ++kk) {
      short8v b = *(const short8v*)((const char*)Wt + lds_off(ct * 16 + lr, kk * 64 + g * 16));
      acc = __builtin_amdgcn_mfma_f32_16x16x32_bf16(a[kk], b, acc, 0, 0, 0);
    }
#pragma unroll
    for (int i = 0; i < 4; ++i)
      *(ushort*)((char*)At + lds_off(w * 16 + g * 4 + i, (ct * 16 + lr) * 2)) = f2bf(acc[i] * dv[i]);
  }
  __syncthreads();

  if constexpr (NREAL == 128) {
#pragma unroll
    for (int it = 0; it < 4; ++it) {
      int cid = tid + it * 256;
      int r = cid >> 4, gg = cid & 15;
      int row = row0 + r;
      if (row < n) {
        short8v t = *(const short8v*)((const char*)At + lds_off(r, gg * 16));
        *(short8v*)&y[(size_t)row * 128 + gg * 8] = t;
      }
    }
  } else {
#pragma unroll
    for (int it = 0; it < 3; ++it) {
      int cid = tid + it * 256;
      if (cid < 640) {
        int r = cid / 10, u = cid - r * 10;
        int row = row0 + r;
        if (row < n) {
          ushort4 t = *(const ushort4*)((const char*)At + lds_off(r, u * 8));
          *(ushort4*)&y[(size_t)row * 40 + u * 4] = t;
        }
      }
    }
  }
}

// ---------------- aggregation (bf16 y gather, fp32 accumulate, 8-deep MLP) ----------------

__global__ __launch_bounds__(256) void agg128_k(const ushort* __restrict__ y, const int* __restrict__ csr,
                                                const int* __restrict__ rowst, const int* __restrict__ deg,
                                                const float* __restrict__ dinv, const float* __restrict__ bias,
                                                float* __restrict__ out, int n) {
  int wid = (blockIdx.x * 256 + threadIdx.x) >> 6;
  if (wid >= n) return;
  int lane = threadIdx.x & 63;
  int base = rowst[wid];
  int dg = deg[wid];
  const uint* yu = (const uint*)y;      // 64 uints (128 bf16) per row
  float p0[8], p1[8];
#pragma unroll
  for (int j = 0; j < 8; ++j) { p0[j] = 0.f; p1[j] = 0.f; }
  int t = 0;
  for (; t + 8 <= dg; t += 8) {
    int sidx[8];
#pragma unroll
    for (int j = 0; j < 8; ++j) sidx[j] = csr[base + t + j];
    uint v[8];
#pragma unroll
    for (int j = 0; j < 8; ++j) v[j] = yu[(size_t)sidx[j] * 64 + lane];
#pragma unroll
    for (int j = 0; j < 8; ++j) {
      p0[j] += __uint_as_float(v[j] << 16);
      p1[j] += __uint_as_float(v[j] & 0xffff0000u);
    }
  }
  for (; t < dg; ++t) {
    int s = csr[base + t];
    uint v = yu[(size_t)s * 64 + lane];
    p0[0] += __uint_as_float(v << 16);
    p1[0] += __uint_as_float(v & 0xffff0000u);
  }
  uint vs = yu[(size_t)wid * 64 + lane];
  p0[0] += __uint_as_float(vs << 16);
  p1[0] += __uint_as_float(vs & 0xffff0000u);
  float s0 = ((p0[0] + p0[1]) + (p0[2] + p0[3])) + ((p0[4] + p0[5]) + (p0[6] + p0[7]));
  float s1 = ((p1[0] + p1[1]) + (p1[2] + p1[3])) + ((p1[4] + p1[5]) + (p1[6] + p1[7]));
  float dvv = dinv[wid];
  float2 bb = *(const float2*)&bias[lane * 2];
  float2 o;
  o.x = fmaf(s0, dvv, bb.x);
  o.y = fmaf(s1, dvv, bb.y);
  *(float2*)&out[(size_t)wid * 128 + lane * 2] = o;
}

__global__ __launch_bounds__(256) void agg40_lsm_k(const ushort* __restrict__ y, const int* __restrict__ csr,
                                                   const int* __restrict__ rowst, const int* __restrict__ deg,
                                                   const float* __restrict__ dinv, const float* __restrict__ bias,
                                                   float* __restrict__ out, int n) {
  int wid = (blockIdx.x * 256 + threadIdx.x) >> 6;
  if (wid >= n) return;
  int lane = threadIdx.x & 63;
  int col = lane < 40 ? lane : 39;
  int base = rowst[wid];
  int dg = deg[wid];
  float a = 0.f, b = 0.f, c = 0.f, d = 0.f;
  int t = 0;
  for (; t + 4 <= dg; t += 4) {
    int s0 = csr[base + t], s1 = csr[base + t + 1], s2 = csr[base + t + 2], s3 = csr[base + t + 3];
    a += bf2f(y[(size_t)s0 * 40 + col]);
    b += bf2f(y[(size_t)s1 * 40 + col]);
    c += bf2f(y[(size_t)s2 * 40 + col]);
    d += bf2f(y[(size_t)s3 * 40 + col]);
  }
  for (; t < dg; ++t) {
    int s = csr[base + t];
    a += bf2f(y[(size_t)s * 40 + col]);
  }
  a += bf2f(y[(size_t)wid * 40 + col]);
  float v = fmaf((a + b) + (c + d), dinv[wid], bias[col]);
  bool act = lane < 40;
  float m = act ? v : -INFINITY;
#pragma unroll
  for (int off = 32; off; off >>= 1) m = fmaxf(m, __shfl_xor(m, off));
  float e = act ? expf(v - m) : 0.f;
  float se = e;
#pragma unroll
  for (int off = 32; off; off >>= 1) se += __shfl_xor(se, off);
  if (act) out[(size_t)wid * 40 + lane] = v - m - logf(se);
}

// ---------------- BN stats ----------------

__global__ __launch_bounds__(256) void stats_partial_k(const float* __restrict__ h,
                                                       float* __restrict__ ps, float* __restrict__ pss, int n) {
  int c = threadIdx.x & 127;
  int half = threadIdx.x >> 7;
  int r0 = blockIdx.x * 2 + half;
  float s = 0.f, ss = 0.f;
  for (int r = r0; r < n; r += 512) {
    float v = h[(size_t)r * 128 + c];
    s += v;
    ss = fmaf(v, v, ss);
  }
  __shared__ float sm[256], sm2[256];
  sm[threadIdx.x] = s;
  sm2[threadIdx.x] = ss;
  __syncthreads();
  if (threadIdx.x < 128) {
    ps[blockIdx.x * 128 + c] = sm[c] + sm[c + 128];
    pss[blockIdx.x * 128 + c] = sm2[c] + sm2[c + 128];
  }
}

__global__ __launch_bounds__(128) void stats_final_k(const float* __restrict__ ps, const float* __restrict__ pss,
                                                     const float* __restrict__ g, const float* __restrict__ be,
                                                     float* __restrict__ scale, float* __restrict__ shift, int n) {
  int c = threadIdx.x;
  float s = 0.f, ss = 0.f;
  for (int b = 0; b < 256; ++b) {
    s += ps[b * 128 + c];
    ss += pss[b * 128 + c];
  }
  float mu = s / (float)n;
  float var = ss / (float)n - mu * mu;
  float rs = rsqrtf(var + EPSV);
  float sc = rs * g[c];
  scale[c] = sc;
  shift[c] = fmaf(-mu, sc, be[c]);
}

// ---------------- launch ----------------

extern "C" void kernel_launch(void* const* d_in, const int* in_sizes, int n_in,
                              void* d_out, int out_size, void* d_ws, size_t ws_size,
                              hipStream_t stream) {
  const float* x   = (const float*)d_in[0];
  const int*   ei  = (const int*)d_in[1];
  const float* W1  = (const float*)d_in[2];
  const float* b1  = (const float*)d_in[3];
  const float* W2  = (const float*)d_in[4];
  const float* b2  = (const float*)d_in[5];
  const float* W3  = (const float*)d_in[6];
  const float* b3  = (const float*)d_in[7];
  const float* g1  = (const float*)d_in[8];
  const float* be1 = (const float*)d_in[9];
  const float* g2  = (const float*)d_in[10];
  const float* be2 = (const float*)d_in[11];
  float* outp = (float*)d_out;

  const int N = NNODES;
  const int E = in_sizes[1] / 2;
  const int NC = (N + 255) / 256;  // 391

  char* w = (char*)d_ws;
  auto alloc = [&](size_t bytes) -> void* {
    void* p = (void*)w;
    w += (bytes + 255) & ~(size_t)255;
    return p;
  };
  int*    deg    = (int*)alloc((size_t)N * 4);
  int*    rowst  = (int*)alloc((size_t)N * 4);
  int*    chunk  = (int*)alloc((size_t)(NC + 1) * 4);
  int*    csr    = (int*)alloc((size_t)E * 4);
  float*  dinv   = (float*)alloc((size_t)N * 4);
  ushort* y      = (ushort*)alloc((size_t)N * 128 * 2);
  float*  hpre   = (float*)alloc((size_t)N * 128 * 4);
  float*  ps     = (float*)alloc((size_t)256 * 128 * 4);
  float*  pss    = (float*)alloc((size_t)256 * 128 * 4);
  float*  scl    = (float*)alloc(128 * 4);
  float*  shf    = (float*)alloc(128 * 4);
  int*    hmatT  = (int*)alloc((size_t)NB * NBLK * 4);
  int*    hbaseT = (int*)alloc((size_t)NB * NBLK * 4);
  int*    boff   = (int*)alloc((size_t)(NB + 1) * 4);
  uint*   ebuf   = (uint*)hpre;  // alias: prep finishes before hpre is written

  // graph prep: radix partition (no global atomics)
  histA_k<<<NBLK, 256, 0, stream>>>(ei, E, hmatT);
  scanM_k<<<1, 256, 0, stream>>>(hmatT, hbaseT, boff, E);
  partB_k<<<NBLK, 256, 0, stream>>>(ei, E, hbaseT, ebuf);
  histnode_k<<<NB, 256, 0, stream>>>(ebuf, boff, deg, N);
  scanA_k<<<NC, 256, 0, stream>>>(deg, rowst, chunk, N);
  scanB_k<<<1, 512, 0, stream>>>(chunk, NC);
  scanC_k<<<NC, 256, 0, stream>>>(deg, chunk, rowst, N);
  dinv_k<<<(N + 255) / 256, 256, 0, stream>>>(deg, dinv, N);
  fillB_k<<<NB, 256, 0, stream>>>(ebuf, boff, rowst, csr, N, E);

  const int GB = (N + 63) / 64;  // 1563
  const int AB = (N + 3) / 4;    // 25000

  // layer 1
  gemm_mfma_k<128, false><<<GB, 256, 0, stream>>>(x, W1, nullptr, nullptr, dinv, y, N);
  agg128_k<<<AB, 256, 0, stream>>>(y, csr, rowst, deg, dinv, b1, hpre, N);
  stats_partial_k<<<256, 256, 0, stream>>>(hpre, ps, pss, N);
  stats_final_k<<<1, 128, 0, stream>>>(ps, pss, g1, be1, scl, shf, N);
  // layer 2
  gemm_mfma_k<128, true><<<GB, 256, 0, stream>>>(hpre, W2, scl, shf, dinv, y, N);
  agg128_k<<<AB, 256, 0, stream>>>(y, csr, rowst, deg, dinv, b2, hpre, N);
  stats_partial_k<<<256, 256, 0, stream>>>(hpre, ps, pss, N);
  stats_final_k<<<1, 128, 0, stream>>>(ps, pss, g2, be2, scl, shf, N);
  // layer 3 + log_softmax
  gemm_mfma_k<40, true><<<GB, 256, 0, stream>>>(hpre, W3, scl, shf, dinv, y, N);
  agg40_lsm_k<<<AB, 256, 0, stream>>>(y, csr, rowst, deg, dinv, b3, outp, N);
}